// Round 2
// baseline (1166.315 us; speedup 1.0000x reference)
//
#include <hip/hip_runtime.h>
#include <math.h>

#define K1 512
#define F1 128
#define F2 40

// ---------------- GEMM1: S1[M,128] = X[M,512] @ W1[512,128] (fp32) -------------
#define G1_BM 64
#define G1_BK 32
__global__ __launch_bounds__(256) void k_gemm1(const float* __restrict__ X,
                                               const float* __restrict__ W,
                                               float* __restrict__ S, int M) {
  __shared__ float As[G1_BK][68];   // transposed [k][row], pad 68 (keeps 16B align, spreads banks)
  __shared__ float Bs[G1_BK][F1];   // [k][col]
  const int t  = threadIdx.x;
  const int m0 = blockIdx.x * G1_BM;
  const int cx = t & 31;            // col group: cols cx*4..+3
  const int ry = t >> 5;            // row group: rows ry*8..+7
  float acc[8][4];
#pragma unroll
  for (int i = 0; i < 8; ++i)
#pragma unroll
    for (int j = 0; j < 4; ++j) acc[i][j] = 0.f;

  for (int k0 = 0; k0 < K1; k0 += G1_BK) {
    // A tile: 64 rows x 32 k = 512 float4, 2 per thread, store transposed
#pragma unroll
    for (int i = 0; i < 2; ++i) {
      int f = t + i * 256;
      int row = f >> 3;
      int kk = (f & 7) << 2;
      float4 a = make_float4(0.f, 0.f, 0.f, 0.f);
      if (m0 + row < M) a = *(const float4*)(X + (size_t)(m0 + row) * K1 + k0 + kk);
      As[kk + 0][row] = a.x;
      As[kk + 1][row] = a.y;
      As[kk + 2][row] = a.z;
      As[kk + 3][row] = a.w;
    }
    // B tile: 32 x 128 = 1024 float4, 4 per thread
#pragma unroll
    for (int i = 0; i < 4; ++i) {
      int f = t + i * 256;
      int row = f >> 5;
      int cc = (f & 31) << 2;
      *(float4*)&Bs[row][cc] = *(const float4*)(W + (size_t)(k0 + row) * F1 + cc);
    }
    __syncthreads();
#pragma unroll
    for (int kk = 0; kk < G1_BK; ++kk) {
      float a[8], b[4];
      *(float4*)&a[0] = *(float4*)&As[kk][ry * 8];
      *(float4*)&a[4] = *(float4*)&As[kk][ry * 8 + 4];
      *(float4*)&b[0] = *(float4*)&Bs[kk][cx * 4];
#pragma unroll
      for (int i = 0; i < 8; ++i)
#pragma unroll
        for (int j = 0; j < 4; ++j) acc[i][j] = fmaf(a[i], b[j], acc[i][j]);
    }
    __syncthreads();
  }
#pragma unroll
  for (int i = 0; i < 8; ++i) {
    int r = m0 + ry * 8 + i;
    if (r < M) {
      float4 o = make_float4(acc[i][0], acc[i][1], acc[i][2], acc[i][3]);
      *(float4*)(S + (size_t)r * F1 + cx * 4) = o;
    }
  }
}

// ---------------- CSR build ----------------------------------------------------
__global__ void k_hist(const int* __restrict__ dst, int* __restrict__ deg, int E) {
  int i = blockIdx.x * blockDim.x + threadIdx.x;
  if (i < E) atomicAdd(&deg[dst[i]], 1);
}

// block of 256 threads scans 1024 elements (4/thread)
__global__ __launch_bounds__(256) void k_scan1(const int* __restrict__ deg,
                                               int* __restrict__ roff,
                                               int* __restrict__ part, int n) {
  __shared__ int wsum[4];
  int t = threadIdx.x, b = blockIdx.x;
  int base = b * 1024 + t * 4;
  int v[4];
#pragma unroll
  for (int i = 0; i < 4; ++i) v[i] = (base + i < n) ? deg[base + i] : 0;
  int tsum = v[0] + v[1] + v[2] + v[3];
  int lane = t & 63, w = t >> 6;
  int inc = tsum;
#pragma unroll
  for (int o = 1; o < 64; o <<= 1) {
    int y = __shfl_up(inc, o);
    if (lane >= o) inc += y;
  }
  if (lane == 63) wsum[w] = inc;
  __syncthreads();
  int wofs = 0;
  for (int i = 0; i < w; ++i) wofs += wsum[i];
  int run = wofs + inc - tsum;  // exclusive within block
#pragma unroll
  for (int i = 0; i < 4; ++i) {
    if (base + i < n) roff[base + i] = run;
    run += v[i];
  }
  if (t == 255) part[b] = wofs + inc;  // block total
}

__global__ __launch_bounds__(256) void k_scan2(int* __restrict__ part, int nblk) {
  __shared__ int wsum[4];
  int t = threadIdx.x;
  int v = (t < nblk) ? part[t] : 0;
  int lane = t & 63, w = t >> 6;
  int inc = v;
#pragma unroll
  for (int o = 1; o < 64; o <<= 1) {
    int y = __shfl_up(inc, o);
    if (lane >= o) inc += y;
  }
  if (lane == 63) wsum[w] = inc;
  __syncthreads();
  int wofs = 0;
  for (int i = 0; i < w; ++i) wofs += wsum[i];
  if (t < nblk) part[t] = wofs + inc - v;  // exclusive
}

__global__ __launch_bounds__(256) void k_scan3(int* __restrict__ roff,
                                               const int* __restrict__ part,
                                               int n, int E) {
  int b = blockIdx.x;
  int add = part[b];
  int base = b * 1024 + threadIdx.x * 4;
#pragma unroll
  for (int i = 0; i < 4; ++i)
    if (base + i < n) roff[base + i] += add;
  if (b == 0 && threadIdx.x == 0) roff[n] = E;
}

__global__ void k_scatter(const int* __restrict__ src, const int* __restrict__ dst,
                          const float* __restrict__ val, int* __restrict__ cur,
                          int* __restrict__ es, float* __restrict__ ev, int E) {
  int i = blockIdx.x * blockDim.x + threadIdx.x;
  if (i < E) {
    int d = dst[i];
    int p = atomicAdd(&cur[d], 1);
    es[p] = src[i];
    ev[p] = val[i];
  }
}

// ---------------- SpMM1 gather (one wave per dst, F=128 -> float2/lane) --------
// H[d] = relu(sum_e val_e * S1[src_e] + b1)
__global__ __launch_bounds__(256) void k_spmm1(const int* __restrict__ roff,
                                               const int* __restrict__ es,
                                               const float* __restrict__ ev,
                                               const float* __restrict__ S1,
                                               const float* __restrict__ b1,
                                               float* __restrict__ H, int Nn) {
  int d = blockIdx.x * 4 + (threadIdx.x >> 6);
  int lane = threadIdx.x & 63;
  if (d >= Nn) return;
  int start = roff[d], end = roff[d + 1];
  float ax = 0.f, ay = 0.f;
  for (int base = start; base < end; base += 64) {
    int nb = end - base;
    if (nb > 64) nb = 64;
    int s = 0;
    float v = 0.f;
    if (base + lane < end) {
      s = es[base + lane];
      v = ev[base + lane];
    }
    int j = 0;
    for (; j + 4 <= nb; j += 4) {
      int s0 = __shfl(s, j), s1 = __shfl(s, j + 1), s2 = __shfl(s, j + 2), s3 = __shfl(s, j + 3);
      float v0 = __shfl(v, j), v1 = __shfl(v, j + 1), v2 = __shfl(v, j + 2), v3 = __shfl(v, j + 3);
      float2 r0 = *(const float2*)(S1 + (size_t)s0 * F1 + lane * 2);
      float2 r1 = *(const float2*)(S1 + (size_t)s1 * F1 + lane * 2);
      float2 r2 = *(const float2*)(S1 + (size_t)s2 * F1 + lane * 2);
      float2 r3 = *(const float2*)(S1 + (size_t)s3 * F1 + lane * 2);
      ax += v0 * r0.x + v1 * r1.x + v2 * r2.x + v3 * r3.x;
      ay += v0 * r0.y + v1 * r1.y + v2 * r2.y + v3 * r3.y;
    }
    for (; j < nb; ++j) {
      int sj = __shfl(s, j);
      float vj = __shfl(v, j);
      float2 r = *(const float2*)(S1 + (size_t)sj * F1 + lane * 2);
      ax += vj * r.x;
      ay += vj * r.y;
    }
  }
  ax = fmaxf(ax + b1[lane * 2], 0.f);
  ay = fmaxf(ay + b1[lane * 2 + 1], 0.f);
  float2 o = make_float2(ax, ay);
  *(float2*)(H + (size_t)d * F1 + lane * 2) = o;
}

// ---------------- GEMM2: S2[M,40] = H[M,128] @ W2[128,40] ----------------------
#define G2_ROWS 64
__global__ __launch_bounds__(320) void k_gemm2(const float* __restrict__ Hm,
                                               const float* __restrict__ W2,
                                               float* __restrict__ S2, int M) {
  __shared__ float Hs[G2_ROWS][132];  // pad 132: bank = (4r+k)%32, spreads rows
  __shared__ float Ws[128][F2];
  const int t = threadIdx.x;
  const int m0 = blockIdx.x * G2_ROWS;
  // stage W2: 1280 float4
#pragma unroll
  for (int i = 0; i < 4; ++i) {
    int f = t + i * 320;
    int k = f / 10;
    int c = (f % 10) * 4;
    *(float4*)&Ws[k][c] = *(const float4*)(W2 + (size_t)k * F2 + c);
  }
  // stage H tile: 2048 float4
  for (int f = t; f < G2_ROWS * 32; f += 320) {
    int row = f >> 5;
    int c4 = (f & 31) << 2;
    float4 hv = make_float4(0.f, 0.f, 0.f, 0.f);
    if (m0 + row < M) hv = *(const float4*)(Hm + (size_t)(m0 + row) * F1 + c4);
    *(float4*)&Hs[row][c4] = hv;
  }
  __syncthreads();
  const int rg = t / 10;  // 0..31 -> rows rg*2, rg*2+1
  const int cg = t % 10;  // cols cg*4..+3
  const int r0 = rg * 2;
  float acc[2][4] = {{0.f, 0.f, 0.f, 0.f}, {0.f, 0.f, 0.f, 0.f}};
#pragma unroll 4
  for (int k = 0; k < 128; ++k) {
    float4 wv = *(float4*)&Ws[k][cg * 4];
    float h0 = Hs[r0][k];
    float h1 = Hs[r0 + 1][k];
    acc[0][0] = fmaf(h0, wv.x, acc[0][0]);
    acc[0][1] = fmaf(h0, wv.y, acc[0][1]);
    acc[0][2] = fmaf(h0, wv.z, acc[0][2]);
    acc[0][3] = fmaf(h0, wv.w, acc[0][3]);
    acc[1][0] = fmaf(h1, wv.x, acc[1][0]);
    acc[1][1] = fmaf(h1, wv.y, acc[1][1]);
    acc[1][2] = fmaf(h1, wv.z, acc[1][2]);
    acc[1][3] = fmaf(h1, wv.w, acc[1][3]);
  }
#pragma unroll
  for (int i = 0; i < 2; ++i) {
    int r = m0 + r0 + i;
    if (r < M) {
      float4 o = make_float4(acc[i][0], acc[i][1], acc[i][2], acc[i][3]);
      *(float4*)(S2 + (size_t)r * F2 + cg * 4) = o;
    }
  }
}

// ---------------- SpMM2 gather + bias + log_softmax (one wave per dst) ---------
__global__ __launch_bounds__(256) void k_spmm2(const int* __restrict__ roff,
                                               const int* __restrict__ es,
                                               const float* __restrict__ ev,
                                               const float* __restrict__ S2,
                                               const float* __restrict__ b2,
                                               float* __restrict__ out, int Nn) {
  int d = blockIdx.x * 4 + (threadIdx.x >> 6);
  int lane = threadIdx.x & 63;
  if (d >= Nn) return;
  int start = roff[d], end = roff[d + 1];
  bool active = lane < F2;
  int col = active ? lane : 0;
  float acc = 0.f;
  for (int base = start; base < end; base += 64) {
    int nb = end - base;
    if (nb > 64) nb = 64;
    int s = 0;
    float v = 0.f;
    if (base + lane < end) {
      s = es[base + lane];
      v = ev[base + lane];
    }
    int j = 0;
    for (; j + 4 <= nb; j += 4) {
      int s0 = __shfl(s, j), s1 = __shfl(s, j + 1), s2 = __shfl(s, j + 2), s3 = __shfl(s, j + 3);
      float v0 = __shfl(v, j), v1 = __shfl(v, j + 1), v2 = __shfl(v, j + 2), v3 = __shfl(v, j + 3);
      float r0 = S2[(size_t)s0 * F2 + col];
      float r1 = S2[(size_t)s1 * F2 + col];
      float r2 = S2[(size_t)s2 * F2 + col];
      float r3 = S2[(size_t)s3 * F2 + col];
      acc += v0 * r0 + v1 * r1 + v2 * r2 + v3 * r3;
    }
    for (; j < nb; ++j) {
      int sj = __shfl(s, j);
      float vj = __shfl(v, j);
      acc += vj * S2[(size_t)sj * F2 + col];
    }
  }
  float val = active ? (acc + b2[col]) : -INFINITY;
  float m = val;
#pragma unroll
  for (int o = 32; o > 0; o >>= 1) m = fmaxf(m, __shfl_xor(m, o));
  float e = active ? expf(val - m) : 0.f;
  float ssum = e;
#pragma unroll
  for (int o = 32; o > 0; o >>= 1) ssum += __shfl_xor(ssum, o);
  if (active) out[(size_t)d * F2 + lane] = val - m - logf(ssum);
}

// ---------------- launch -------------------------------------------------------
extern "C" void kernel_launch(void* const* d_in, const int* in_sizes, int n_in,
                              void* d_out, int out_size, void* d_ws, size_t ws_size,
                              hipStream_t stream) {
  const float* x    = (const float*)d_in[0];
  const int*   esrc = (const int*)d_in[1];
  const int*   edst = (const int*)d_in[2];
  const float* evl  = (const float*)d_in[3];
  const float* W1   = (const float*)d_in[4];
  const float* b1   = (const float*)d_in[5];
  const float* W2   = (const float*)d_in[6];
  const float* b2   = (const float*)d_in[7];
  const int E  = in_sizes[1];
  const int Nn = in_sizes[0] / K1;
  float* out = (float*)d_out;

  char* ws = (char*)d_ws;
  float* S1  = (float*)ws;                              // N*128 f32, later reused as S2 (N*40)
  float* Hm  = (float*)(ws + (size_t)Nn * F1 * 4);      // N*128 f32
  int*   roff = (int*)(ws + (size_t)Nn * F1 * 8);       // N+1
  int*   cur  = roff + (Nn + 1);                        // N+1 (deg, then cursors)
  int*   es   = cur + (Nn + 1);                         // E
  float* ev   = (float*)(es + E);                       // E
  int*   part = (int*)(ev + E);                         // <=256

  // ---- CSR build (reused by both spmm layers) ----
  hipMemsetAsync(cur, 0, (size_t)(Nn + 1) * 4, stream);
  int hb = (E + 255) / 256;
  k_hist<<<hb, 256, 0, stream>>>(edst, cur, E);
  int nblk = (Nn + 1023) / 1024;
  k_scan1<<<nblk, 256, 0, stream>>>(cur, roff, part, Nn);
  k_scan2<<<1, 256, 0, stream>>>(part, nblk);
  k_scan3<<<nblk, 256, 0, stream>>>(roff, part, Nn, E);
  hipMemcpyAsync(cur, roff, (size_t)Nn * 4, hipMemcpyDeviceToDevice, stream);
  k_scatter<<<hb, 256, 0, stream>>>(esrc, edst, evl, cur, es, ev, E);

  // ---- layer 1 ----
  k_gemm1<<<(Nn + G1_BM - 1) / G1_BM, 256, 0, stream>>>(x, W1, S1, Nn);
  k_spmm1<<<(Nn + 3) / 4, 256, 0, stream>>>(roff, es, ev, S1, b1, Hm, Nn);
  // ---- layer 2 ----
  k_gemm2<<<(Nn + G2_ROWS - 1) / G2_ROWS, 320, 0, stream>>>(Hm, W2, S1, Nn);
  k_spmm2<<<(Nn + 3) / 4, 256, 0, stream>>>(roff, es, ev, S1, b2, out, Nn);
}